// Round 6
// baseline (143.744 us; speedup 1.0000x reference)
//
#include <hip/hip_runtime.h>

#define SEQ 4096
#define DIM 64
#define HC 64            // half-chunk (recurrence granularity)
#define NHC 64           // SEQ/HC
#define EPSV 1e-10f
#define KS_OFF 4194304   // float offset of ksum region (S region = 2048 states * 4096 bf16 = 16.78 MB)

typedef __attribute__((ext_vector_type(8))) short s16x8;   // 8 bf16 (4 VGPRs)
typedef __attribute__((ext_vector_type(4))) float f32x4;   // MFMA C/D

__device__ __forceinline__ unsigned short f2bf(float f) {
  unsigned int u = __float_as_uint(f);
  u += 0x7FFF + ((u >> 16) & 1);          // RNE (inputs finite)
  return (unsigned short)(u >> 16);
}
__device__ __forceinline__ float bf2f(unsigned short s) {
  return __uint_as_float(((unsigned int)s) << 16);
}
__device__ __forceinline__ s16x8 pack8(float4 a, float4 b) {
  s16x8 r;
  r[0] = (short)f2bf(a.x); r[1] = (short)f2bf(a.y); r[2] = (short)f2bf(a.z); r[3] = (short)f2bf(a.w);
  r[4] = (short)f2bf(b.x); r[5] = (short)f2bf(b.y); r[6] = (short)f2bf(b.z); r[7] = (short)f2bf(b.w);
  return r;
}

// stage 64x64 fp32 global tile -> natural bf16 rows (stride 72). Conflict-free b64 writes.
__device__ __forceinline__ void stage_nat64(const float* __restrict__ gp,
                                            unsigned short* __restrict__ nat, int t) {
#pragma unroll
  for (int p = 0; p < 4; ++p) {
    int idx = t + p * 256;               // 1024 float4 = 64x64 fp32
    int i = idx >> 4, d4 = idx & 15;
    float4 x = ((const float4*)gp)[idx];
    ushort4 u = make_ushort4(f2bf(x.x), f2bf(x.y), f2bf(x.z), f2bf(x.w));
    *(ushort4*)&nat[i * 72 + d4 * 4] = u;
  }
}

// transpose natural (64 x 64, stride 72) -> T (64 x 64, stride 72). Conflict-free reads
// (lane d = L, consecutive shorts -> 32 dwords broadcast-paired), b128 writes.
__device__ __forceinline__ void transpose64(const unsigned short* __restrict__ nat,
                                            unsigned short* __restrict__ dst, int t) {
  int L = t & 63, w = t >> 6;
#pragma unroll
  for (int it = 0; it < 2; ++it) {
    int d = L, j8 = it * 4 + w;
    s16x8 seg;
#pragma unroll
    for (int u = 0; u < 8; ++u) seg[u] = (short)nat[(j8 * 8 + u) * 72 + d];
    *(s16x8*)&dst[d * 72 + j8 * 8] = seg;
  }
}

// ---------------- Pass A: per-half-chunk S^T[e][d] = sum_j v[j][e] k[j][d]; bf16 out ------------
__global__ __launch_bounds__(256) void pass_a(const float* __restrict__ k0,
                                              const float* __restrict__ k1,
                                              const float* __restrict__ v,
                                              float* __restrict__ ws) {
  __shared__ __align__(16) unsigned short skT[64 * 72];
  __shared__ __align__(16) unsigned short svT[64 * 72];
  __shared__ __align__(16) unsigned short snat[64 * 72];
  int bid = blockIdx.x;                        // m*1024 + hh*64 + hc
  int m = bid >> 10, hh = (bid >> 6) & 15, hc = bid & 63;
  const float* kp = (m ? k1 : k0) + (size_t)hh * SEQ * DIM + (size_t)hc * HC * DIM;
  const float* vp = v + (size_t)hh * SEQ * DIM + (size_t)hc * HC * DIM;
  int t = threadIdx.x;

  stage_nat64(kp, snat, t);
  __syncthreads();
  transpose64(snat, skT, t);
  __syncthreads();
  stage_nat64(vp, snat, t);
  __syncthreads();
  transpose64(snat, svT, t);
  __syncthreads();

  // ksum[d] = sum_j k[j][d] (row-sum of kT)
  if (t < 64) {
    float s = 0.f;
#pragma unroll
    for (int it = 0; it < 8; ++it) {
      s16x8 blk = *(const s16x8*)&skT[t * 72 + it * 8];
#pragma unroll
      for (int u = 0; u < 8; ++u) s += bf2f((unsigned short)blk[u]);
    }
    ws[KS_OFF + (size_t)bid * 64 + t] = s;
  }

  int w = t >> 6, L = t & 63, g = L >> 4, cL = L & 15;
  f32x4 acc[4];
#pragma unroll
  for (int ct = 0; ct < 4; ++ct) acc[ct] = (f32x4){0.f, 0.f, 0.f, 0.f};
#pragma unroll
  for (int ks = 0; ks < 2; ++ks) {
    s16x8 aF = *(const s16x8*)&svT[(w * 16 + cL) * 72 + ks * 32 + g * 8];
#pragma unroll
    for (int ct = 0; ct < 4; ++ct) {
      s16x8 bF = *(const s16x8*)&skT[(ct * 16 + cL) * 72 + ks * 32 + g * 8];
      acc[ct] = __builtin_amdgcn_mfma_f32_16x16x32_bf16(aF, bF, acc[ct], 0, 0, 0);
    }
  }
  unsigned short* Sp = (unsigned short*)ws + (size_t)bid * 4096;
#pragma unroll
  for (int ct = 0; ct < 4; ++ct)
#pragma unroll
    for (int r = 0; r < 4; ++r)
      Sp[(size_t)(w * 16 + g * 4 + r) * 64 + ct * 16 + cL] = f2bf(acc[ct][r]);
}

// ---------------- Pass B: exclusive prefix over 64 half-chunks; all loads in flight -------------
__global__ __launch_bounds__(256) void pass_b(float* __restrict__ ws) {
  int t = threadIdx.x;
  if (blockIdx.x < 256) {                       // S region: u32 = 2 bf16 lanes
    int gid = blockIdx.x * 256 + t;             // [0, 65536)
    int mh = gid >> 11, de2 = gid & 2047;       // mh in [0,32)
    unsigned int* p = (unsigned int*)ws + (size_t)mh * NHC * 2048 + de2;
    unsigned int x[NHC];
#pragma unroll
    for (int c = 0; c < NHC; ++c) x[c] = p[(size_t)c * 2048];
    float r0 = 0.f, r1 = 0.f;
#pragma unroll
    for (int c = 0; c < NHC; ++c) {
      unsigned int xc = x[c];
      p[(size_t)c * 2048] = (unsigned int)f2bf(r0) | ((unsigned int)f2bf(r1) << 16);
      r0 += bf2f((unsigned short)(xc & 0xFFFF));
      r1 += bf2f((unsigned short)(xc >> 16));
    }
  } else {                                      // ksum (fp32)
    int gid = (blockIdx.x - 256) * 256 + t;     // [0, 2048)
    int mh = gid >> 6, d = gid & 63;
    float* p = ws + KS_OFF + (size_t)mh * NHC * 64 + d;
    float x[NHC];
#pragma unroll
    for (int c = 0; c < NHC; ++c) x[c] = p[(size_t)c * 64];
    float run = 0.f;
#pragma unroll
    for (int c = 0; c < NHC; ++c) {
      p[(size_t)c * 64] = run;
      run += x[c];
    }
  }
}

// ---------------- Pass C: per-half-chunk output; 4 waves, wave w -> row-tile w ------------------
__global__ __launch_bounds__(256, 4) void pass_c(const float* __restrict__ q0,
                                                 const float* __restrict__ q1,
                                                 const float* __restrict__ k0,
                                                 const float* __restrict__ k1,
                                                 const float* __restrict__ v,
                                                 const float* __restrict__ ws,
                                                 float* __restrict__ out) {
  __shared__ __align__(16) unsigned short svT[64 * 72];  // vT[e][j], own 64 j's
  __shared__ __align__(16) unsigned short sun[64 * 72];  // v-nat, then per-map ST (stride 72) / P (stride 40)
  __shared__ float skpref[64];
  __shared__ float sden[64];

  int hh = blockIdx.x >> 6, hc = blockIdx.x & 63;
  int t = threadIdx.x;
  int w = t >> 6, L = t & 63, g = L >> 4, cL = L & 15;
  size_t off = (size_t)hh * SEQ * DIM + (size_t)hc * HC * DIM;

  stage_nat64(v + off, sun, t);
  __syncthreads();
  transpose64(sun, svT, t);

  f32x4 accO[4];
#pragma unroll
  for (int b = 0; b < 4; ++b) accO[b] = (f32x4){0.f, 0.f, 0.f, 0.f};
  float denfrag[4] = {};
  float denp = 0.f;

  const unsigned short* Sbase = (const unsigned short*)ws;

  for (int m = 0; m < 2; ++m) {
    const float* qp = (m ? q1 : q0) + off;
    const float* kp = (m ? k1 : k0) + off;
    int sid = m * 1024 + hh * 64 + hc;
    const unsigned short* Sp = Sbase + (size_t)sid * 4096;
    const float* Kp = ws + KS_OFF + (size_t)sid * 64;

    __syncthreads();  // m=0: transpose reads of sun done; m=1: all P reads done
#pragma unroll
    for (int p2 = 0; p2 < 2; ++p2) {
      int idx = t + p2 * 256;                  // 512 x 16B = 64x64 bf16 ST
      int e = idx >> 3, seg = idx & 7;
      *(s16x8*)&sun[e * 72 + seg * 8] = ((const s16x8*)Sp)[idx];
    }
    if (t < 64) skpref[t] = Kp[t];
    __syncthreads();

    // ksum_prefix fragment for this lane's 16 d's
    float kpf[2][8];
#pragma unroll
    for (int h = 0; h < 2; ++h) {
      float4 c0 = *(const float4*)&skpref[h * 32 + g * 8];
      float4 c1 = *(const float4*)&skpref[h * 32 + g * 8 + 4];
      kpf[h][0] = c0.x; kpf[h][1] = c0.y; kpf[h][2] = c0.z; kpf[h][3] = c0.w;
      kpf[h][4] = c1.x; kpf[h][5] = c1.y; kpf[h][6] = c1.z; kpf[h][7] = c1.w;
    }

    // q A-frag direct from global (row = w*16 + cL); den partial with fp32 q
    s16x8 aq[2];
    {
      int rl = w * 16 + cL;
#pragma unroll
      for (int h = 0; h < 2; ++h) {
        const float* qa = qp + rl * 64 + h * 32 + g * 8;
        float4 a0 = *(const float4*)qa;
        float4 a1 = *(const float4*)(qa + 4);
        denp += a0.x * kpf[h][0] + a0.y * kpf[h][1] + a0.z * kpf[h][2] + a0.w * kpf[h][3]
              + a1.x * kpf[h][4] + a1.y * kpf[h][5] + a1.z * kpf[h][6] + a1.w * kpf[h][7];
        aq[h] = pack8(a0, a1);
      }
    }

    // inter: O += q @ S_prefix
#pragma unroll
    for (int h = 0; h < 2; ++h) {
#pragma unroll
      for (int et = 0; et < 4; ++et) {
        s16x8 bS = *(const s16x8*)&sun[(et * 16 + cL) * 72 + h * 32 + g * 8];
        accO[et] = __builtin_amdgcn_mfma_f32_16x16x32_bf16(aq[h], bS, accO[et], 0, 0, 0);
      }
    }
    __syncthreads();  // ST reads complete before P strips overwrite sun

    // intra: strips of 32 j's within own half-chunk; wave w needs s <= w>>1
    for (int s = 0; s <= (w >> 1); ++s) {
      s16x8 bK[2][2];
#pragma unroll
      for (int ct01 = 0; ct01 < 2; ++ct01) {
        int jrow = (2 * s + ct01) * 16 + cL;
#pragma unroll
        for (int h = 0; h < 2; ++h) {
          const float* ka = kp + jrow * 64 + h * 32 + g * 8;
          float4 b0 = *(const float4*)ka;
          float4 b1 = *(const float4*)(ka + 4);
          bK[ct01][h] = pack8(b0, b1);
        }
      }
      int rowbase = w * 16 + g * 4;
#pragma unroll
      for (int ct01 = 0; ct01 < 2; ++ct01) {
        int jt = 2 * s + ct01;
        if (jt > w) {                           // fully masked half: zero-fill P
#pragma unroll
          for (int r = 0; r < 4; ++r) sun[(rowbase + r) * 40 + ct01 * 16 + cL] = 0;
        } else {
          f32x4 C = (f32x4){0.f, 0.f, 0.f, 0.f};
          C = __builtin_amdgcn_mfma_f32_16x16x32_bf16(aq[0], bK[ct01][0], C, 0, 0, 0);
          C = __builtin_amdgcn_mfma_f32_16x16x32_bf16(aq[1], bK[ct01][1], C, 0, 0, 0);
          if (jt == w) {                        // diagonal: keep col <= row
#pragma unroll
            for (int r = 0; r < 4; ++r)
              if (cL > g * 4 + r) C[r] = 0.f;
          }
#pragma unroll
          for (int r = 0; r < 4; ++r) {
            denfrag[r] += C[r];
            sun[(rowbase + r) * 40 + ct01 * 16 + cL] = f2bf(C[r]);
          }
        }
      }
      asm volatile("s_waitcnt lgkmcnt(0)" ::: "memory");  // wave-private P rows visible

      s16x8 aP = *(const s16x8*)&sun[(w * 16 + cL) * 40 + g * 8];
#pragma unroll
      for (int et = 0; et < 4; ++et) {
        s16x8 bV = *(const s16x8*)&svT[(et * 16 + cL) * 72 + s * 32 + g * 8];
        accO[et] = __builtin_amdgcn_mfma_f32_16x16x32_bf16(aP, bV, accO[et], 0, 0, 0);
      }
    }
  }

  // den(qk) reduce over the 4 g-quads -> per row
  denp += __shfl_xor(denp, 16);
  denp += __shfl_xor(denp, 32);
  if (L < 16) sden[w * 16 + L] = denp;
  __syncthreads();

  float* op = out + off;
#pragma unroll
  for (int r = 0; r < 4; ++r) {
    float vs = denfrag[r];
    vs += __shfl_xor(vs, 1);
    vs += __shfl_xor(vs, 2);
    vs += __shfl_xor(vs, 4);
    vs += __shfl_xor(vs, 8);
    int rl = w * 16 + g * 4 + r;
    float inv = 1.f / (sden[rl] + vs + EPSV);
#pragma unroll
    for (int et = 0; et < 4; ++et)
      op[(size_t)rl * 64 + et * 16 + cL] = accO[et][r] * inv;
  }
}

extern "C" void kernel_launch(void* const* d_in, const int* in_sizes, int n_in,
                              void* d_out, int out_size, void* d_ws, size_t ws_size,
                              hipStream_t stream) {
  const float* q  = (const float*)d_in[0];
  const float* k  = (const float*)d_in[1];
  const float* qr = (const float*)d_in[2];
  const float* kr = (const float*)d_in[3];
  const float* v  = (const float*)d_in[4];
  float* out = (float*)d_out;
  float* ws  = (float*)d_ws;

  hipLaunchKernelGGL(pass_a, dim3(2048), dim3(256), 0, stream, k, kr, v, ws);
  hipLaunchKernelGGL(pass_b, dim3(264), dim3(256), 0, stream, ws);
  hipLaunchKernelGGL(pass_c, dim3(1024), dim3(256), 0, stream, q, qr, k, kr, v, ws, out);
}